// Round 1
// baseline (518.501 us; speedup 1.0000x reference)
//
#include <hip/hip_runtime.h>
#include <hip/hip_bf16.h>

typedef _Float16 f16;
typedef __attribute__((ext_vector_type(8))) _Float16 half8;
typedef __attribute__((ext_vector_type(4))) _Float16 half4;
typedef __attribute__((ext_vector_type(4))) float f32x4;

#define AS1 __attribute__((address_space(1)))
#define AS3 __attribute__((address_space(3)))

constexpr int CH  = 512;    // channels
constexpr int NSP = 4096;   // 64*64 spatial
constexpr int NB  = 4;      // batch

__device__ __forceinline__ void gload_lds16(const void* g, void* l) {
    __builtin_amdgcn_global_load_lds((const AS1 void*)g, (AS3 void*)l, 16, 0, 0);
}

// ---------------------------------------------------------------- stats
// per-(b,c) mean & 1/sqrt(var_unbiased+eps) for content (rows 0..2047) and style (2048..4095)
// stats layout: [0:2048) c_mean, [2048:4096) c_istd, [4096:6144) s_mean, [6144:8192) s_istd
__global__ void stats_kernel(const float* __restrict__ c_, const float* __restrict__ s_,
                             float* __restrict__ stats)
{
    int row = blockIdx.x;
    const float* p = ((row < NB*CH) ? c_ : s_) + (size_t)(row & (NB*CH - 1)) * NSP;
    float s = 0.f, ss = 0.f;
    for (int i = threadIdx.x; i < NSP/4; i += 256) {
        float4 v = ((const float4*)p)[i];
        s  += v.x + v.y + v.z + v.w;
        ss += v.x*v.x + v.y*v.y + v.z*v.z + v.w*v.w;
    }
    #pragma unroll
    for (int off = 32; off; off >>= 1) { s += __shfl_down(s, off); ss += __shfl_down(ss, off); }
    __shared__ float r1[4], r2[4];
    if ((threadIdx.x & 63) == 0) { r1[threadIdx.x >> 6] = s; r2[threadIdx.x >> 6] = ss; }
    __syncthreads();
    if (threadIdx.x == 0) {
        s = r1[0]+r1[1]+r1[2]+r1[3]; ss = r2[0]+r2[1]+r2[2]+r2[3];
        float mean = s * (1.f/NSP);
        float var  = (ss - (float)NSP*mean*mean) * (1.f/(NSP-1));
        int base = (row < NB*CH) ? 0 : 2*NB*CH;
        int r = row & (NB*CH - 1);
        stats[base + r] = mean;
        stats[base + NB*CH + r] = rsqrtf(var + 1e-5f);
    }
}

// ---------------------------------------------------------------- effective weights
// mode 0: fw_e[b][o][c]=f_w*istd_c, fb_e[b][o]=f_b-sum(f_w*mean*istd)  (content stats)
// mode 1: same for g with style stats; mode 2/3: plain f16 convert of h_w / out_w (b==0 only)
__global__ void effw_kernel(const float* __restrict__ fw, const float* __restrict__ fb,
                            const float* __restrict__ gw, const float* __restrict__ gb,
                            const float* __restrict__ hw, const float* __restrict__ ow,
                            const float* __restrict__ stats,
                            f16* __restrict__ fw_e, float* __restrict__ fb_e,
                            f16* __restrict__ gw_e, float* __restrict__ gb_e,
                            f16* __restrict__ hw_h, f16* __restrict__ ow_h)
{
    int o = blockIdx.x, b = blockIdx.y, mode = blockIdx.z, t = threadIdx.x;
    if (mode >= 2) {
        if (b != 0) return;
        const float* srcw = (mode == 2) ? hw : ow;
        f16* dstw = (mode == 2) ? hw_h : ow_h;
        for (int c = t; c < CH; c += 128) dstw[o*CH + c] = (f16)srcw[o*CH + c];
        return;
    }
    const float* w  = mode ? gw : fw;
    const float* st = stats + (mode ? 2*NB*CH : 0);
    f16* we = mode ? gw_e : fw_e;
    float part = 0.f;
    for (int c = t; c < CH; c += 128) {
        float mn = st[b*CH + c], is = st[NB*CH + b*CH + c];
        float wv = w[o*CH + c];
        we[((size_t)b*CH + o)*CH + c] = (f16)(wv * is);
        part += wv * mn * is;
    }
    #pragma unroll
    for (int off = 32; off; off >>= 1) part += __shfl_down(part, off);
    __shared__ float rr[2];
    if ((t & 63) == 0) rr[t >> 6] = part;
    __syncthreads();
    if (t == 0) (mode ? gb_e : fb_e)[b*CH + o] = (mode ? gb : fb)[o] - (rr[0] + rr[1]);
}

// ---------------------------------------------------------------- transpose f32[c][n] -> f16[n][c]
__global__ void transpose_f16_kernel(const float* __restrict__ content, const float* __restrict__ style,
                                     f16* __restrict__ content_t, f16* __restrict__ style_t)
{
    int b = blockIdx.z & 3, is_style = blockIdx.z >> 2;
    const float* src = (is_style ? style : content) + (size_t)b * CH * NSP;
    f16* dst = (is_style ? style_t : content_t) + (size_t)b * NSP * CH;
    int c0 = blockIdx.y * 64, n0 = blockIdx.x * 64;
    __shared__ f16 tile[64][72];
    int t = threadIdx.x;
    #pragma unroll
    for (int i = 0; i < 4; i++) {
        int idx = t + i*256;
        int cr = idx >> 4, n4 = (idx & 15) * 4;
        float4 v = *(const float4*)(src + (size_t)(c0+cr)*NSP + n0 + n4);
        tile[cr][n4+0] = (f16)v.x; tile[cr][n4+1] = (f16)v.y;
        tile[cr][n4+2] = (f16)v.z; tile[cr][n4+3] = (f16)v.w;
    }
    __syncthreads();
    int nr = t >> 2, seg = (t & 3) * 16;
    __align__(16) f16 out_v[16];
    #pragma unroll
    for (int j = 0; j < 16; j++) out_v[j] = tile[seg + j][nr];
    f16* dp = dst + (size_t)(n0+nr)*CH + c0 + seg;
    *(int4*)dp = ((int4*)out_v)[0];
    *(int4*)(dp + 8) = ((int4*)out_v)[1];
}

// ---------------------------------------------------------------- GEMM  Y[o][n] = sum_c W[o][c]*Xt[n][c] + bias[o]
// MODE 0: store f16 transposed Y_t[n][o]; MODE 1: store f16 Y[o][n]; MODE 2: store f32 Y[o][n]
// 128x128 tile, BK=64, 4 waves (2x2 of 64x64), global_load_lds + XOR swizzle (rows of 128B, bits 4..6 ^= row&7)
template<int MODE>
__global__ __launch_bounds__(256)
void gemm_kernel(const f16* __restrict__ W, long wstrideb,
                 const f16* __restrict__ Xt,
                 const float* __restrict__ bias, long bstrideb,
                 void* __restrict__ Y, long ystrideb)
{
    const int z = blockIdx.z;
    W    += (size_t)z * wstrideb;
    Xt   += (size_t)z * NSP * CH;
    bias += (size_t)z * bstrideb;
    const int m0 = blockIdx.y * 128, n0 = blockIdx.x * 128;
    const int t = threadIdx.x, wave = t >> 6, lane = t & 63;
    const int l15 = lane & 15, l4 = lane >> 4;
    const int wm = (wave >> 1) * 64, wn = (wave & 1) * 64;

    __shared__ __align__(16) f16 Al[2][8192];   // [128 rows][64 c], swizzled
    __shared__ __align__(16) f16 Bl[2][8192];

    f32x4 acc[4][4] = {};

    auto stage = [&](int bufi, int kk) {
        #pragma unroll
        for (int j = 0; j < 4; j++) {
            int L  = ((wave*4 + j)*64 + lane) * 16;          // linear LDS byte
            int SL = L ^ (((L >> 7) & 7) << 4);              // pre-swizzled source position
            int row = SL >> 7, seg = (SL & 127) >> 1;        // row 0..127, elem 0..63
            gload_lds16(W  + (size_t)(m0 + row)*CH + kk + seg, &Al[bufi][L >> 1]);
            gload_lds16(Xt + (size_t)(n0 + row)*CH + kk + seg, &Bl[bufi][L >> 1]);
        }
    };

    stage(0, 0);
    __syncthreads();
    for (int ks = 0; ks < 8; ks++) {
        int bufi = ks & 1;
        if (ks < 7) stage(bufi ^ 1, (ks + 1) * 64);
        #pragma unroll
        for (int kb = 0; kb < 2; kb++) {
            half8 a[4], bb[4];
            #pragma unroll
            for (int i = 0; i < 4; i++) {
                int ab = (wm + i*16 + l15)*128 + kb*64 + l4*16;
                ab ^= ((ab >> 7) & 7) << 4;
                a[i] = *(const half8*)&Al[bufi][ab >> 1];
                int bby = (wn + i*16 + l15)*128 + kb*64 + l4*16;
                bby ^= ((bby >> 7) & 7) << 4;
                bb[i] = *(const half8*)&Bl[bufi][bby >> 1];
            }
            #pragma unroll
            for (int i = 0; i < 4; i++)
                #pragma unroll
                for (int jj = 0; jj < 4; jj++)
                    acc[i][jj] = __builtin_amdgcn_mfma_f32_16x16x32_f16(a[i], bb[jj], acc[i][jj], 0, 0, 0);
        }
        __syncthreads();
    }

    #pragma unroll
    for (int i = 0; i < 4; i++) {
        const int ob = m0 + wm + i*16 + l4*4;                // o base (4 consecutive via reg idx)
        f32x4 bv = *(const f32x4*)(bias + ob);
        #pragma unroll
        for (int jj = 0; jj < 4; jj++) {
            const int n = n0 + wn + jj*16 + l15;
            f32x4 v = acc[i][jj];
            v[0] += bv[0]; v[1] += bv[1]; v[2] += bv[2]; v[3] += bv[3];
            if constexpr (MODE == 0) {
                f16* Yb = (f16*)Y + (size_t)z * ystrideb;
                half4 pk; pk[0]=(f16)v[0]; pk[1]=(f16)v[1]; pk[2]=(f16)v[2]; pk[3]=(f16)v[3];
                *(half4*)(Yb + (size_t)n * CH + ob) = pk;
            } else if constexpr (MODE == 1) {
                f16* Yb = (f16*)Y + (size_t)z * ystrideb;
                #pragma unroll
                for (int r = 0; r < 4; r++) Yb[(size_t)(ob + r) * NSP + n] = (f16)v[r];
            } else {
                float* Yf = (float*)Y + (size_t)z * ystrideb;
                #pragma unroll
                for (int r = 0; r < 4; r++) Yf[(size_t)(ob + r) * NSP + n] = v[r];
            }
        }
    }
}

// ---------------------------------------------------------------- flash attention
// styled_t[n][c] = sum_m softmax_m( sum_c' Ft[n][c'] Gt[m][c'] ) * H[c][m]
// block: batch b, 64 q-rows; 4 waves x 16 rows. Q in regs. K/V staged in 16KB c-chunks, dbuf, swizzled.
__global__ __launch_bounds__(256, 1)
void flash_kernel(const f16* __restrict__ Ft, const f16* __restrict__ Gt,
                  const f16* __restrict__ Hm, f16* __restrict__ So)
{
    const int b = blockIdx.y;
    const int n0 = blockIdx.x * 64;
    const int t = threadIdx.x, wave = t >> 6, lane = t & 63;
    const int l15 = lane & 15, l4 = lane >> 4;
    const int nw = n0 + wave * 16;

    __shared__ __align__(16) f16 KV[2][8192];        // K: [64 m][128 c] (256B rows) / V: [128 c][64 m] (128B rows)
    __shared__ __align__(16) f16 P_lds[4][16][72];   // per-wave P, padded rows

    // Q resident: 16 frags x 8 f16; lane l: row = nw + l15, k = kb*32 + l4*8 + j
    half8 q[16];
    {
        const f16* qp = Ft + ((size_t)b*NSP + nw + l15) * CH + l4*8;
        #pragma unroll
        for (int kb = 0; kb < 16; kb++) q[kb] = *(const half8*)(qp + kb*32);
    }

    f32x4 o_acc[32] = {};                // D rows = n (4*l4+reg), cols = c (i*16+l15)
    float mrun[4] = {-1e30f,-1e30f,-1e30f,-1e30f};
    float lrun[4] = {0.f,0.f,0.f,0.f};

    const f16* Gb = Gt + (size_t)b * NSP * CH;
    const f16* Hb = Hm + (size_t)b * CH * NSP;

    auto stageK = [&](int bufi, int mm0, int cc) {    // rows of 256B: swizzle bits4..6 ^= (byte>>8)&7
        #pragma unroll
        for (int j = 0; j < 4; j++) {
            int L  = ((wave*4 + j)*64 + lane) * 16;
            int SL = L ^ (((L >> 8) & 7) << 4);
            gload_lds16(Gb + (size_t)(mm0 + (SL >> 8)) * CH + cc*128 + ((SL & 255) >> 1),
                        &KV[bufi][L >> 1]);
        }
    };
    auto stageV = [&](int bufi, int mm0, int cc) {    // rows of 128B: swizzle bits4..6 ^= (byte>>7)&7
        #pragma unroll
        for (int j = 0; j < 4; j++) {
            int L  = ((wave*4 + j)*64 + lane) * 16;
            int SL = L ^ (((L >> 7) & 7) << 4);
            gload_lds16(Hb + (size_t)(cc*128 + (SL >> 7)) * NSP + mm0 + ((SL & 127) >> 1),
                        &KV[bufi][L >> 1]);
        }
    };

    int buf = 0;
    stageK(0, 0, 0);
    __syncthreads();

    for (int m0 = 0; m0 < NSP; m0 += 64) {
        const int nm0 = (m0 + 64 < NSP) ? (m0 + 64) : 0;
        f32x4 s[4] = {};

        // ---- S = Q K^T over 4 c-chunks of 128
        #pragma unroll
        for (int cc = 0; cc < 4; cc++) {
            if (cc < 3) stageK(buf ^ 1, m0, cc + 1);
            else        stageV(buf ^ 1, m0, 0);
            #pragma unroll
            for (int kb = 0; kb < 4; kb++) {
                half8 a = q[cc*4 + kb];
                #pragma unroll
                for (int mc = 0; mc < 4; mc++) {
                    int byt = (mc*16 + l15)*256 + kb*64 + l4*16;
                    byt ^= ((byt >> 8) & 7) << 4;
                    half8 bb = *(const half8*)&KV[buf][byt >> 1];
                    s[mc] = __builtin_amdgcn_mfma_f32_16x16x32_f16(a, bb, s[mc], 0, 0, 0);
                }
            }
            __syncthreads();
            buf ^= 1;
        }

        // ---- online softmax; lane holds S[n=4*l4+r][m = m0 + mc*16 + l15]
        float scale_[4];
        #pragma unroll
        for (int r = 0; r < 4; r++) {
            float mx = fmaxf(fmaxf(s[0][r], s[1][r]), fmaxf(s[2][r], s[3][r]));
            #pragma unroll
            for (int off = 8; off; off >>= 1) mx = fmaxf(mx, __shfl_xor(mx, off));
            float mnew = fmaxf(mrun[r], mx);
            scale_[r] = __expf(mrun[r] - mnew);
            float ps = 0.f;
            #pragma unroll
            for (int mc = 0; mc < 4; mc++) {
                float p = __expf(s[mc][r] - mnew);
                s[mc][r] = p; ps += p;
            }
            #pragma unroll
            for (int off = 8; off; off >>= 1) ps += __shfl_xor(ps, off);
            lrun[r] = lrun[r] * scale_[r] + ps;
            mrun[r] = mnew;
        }
        // P -> LDS (own wave only)
        #pragma unroll
        for (int mc = 0; mc < 4; mc++)
            #pragma unroll
            for (int r = 0; r < 4; r++)
                P_lds[wave][l4*4 + r][mc*16 + l15] = (f16)s[mc][r];
        // rescale O (rows match reg index r directly)
        #pragma unroll
        for (int i = 0; i < 32; i++) {
            o_acc[i][0] *= scale_[0]; o_acc[i][1] *= scale_[1];
            o_acc[i][2] *= scale_[2]; o_acc[i][3] *= scale_[3];
        }
        __syncthreads();   // safety: P_lds write->read ordering; no cross-wave hazard otherwise

        // ---- O += P * V over 4 c-chunks of 128 (A = P frag, B = V frag)
        #pragma unroll
        for (int vcc = 0; vcc < 4; vcc++) {
            if (vcc < 3) stageV(buf ^ 1, m0, vcc + 1);
            else         stageK(buf ^ 1, nm0, 0);
            #pragma unroll
            for (int kb = 0; kb < 2; kb++) {
                half8 pb = *(const half8*)&P_lds[wave][l15][kb*32 + l4*8];
                #pragma unroll
                for (int cb = 0; cb < 8; cb++) {
                    int ab = (cb*16 + l15)*128 + kb*64 + l4*16;
                    ab ^= ((ab >> 7) & 7) << 4;
                    half8 vv = *(const half8*)&KV[buf][ab >> 1];
                    o_acc[vcc*8 + cb] = __builtin_amdgcn_mfma_f32_16x16x32_f16(pb, vv, o_acc[vcc*8 + cb], 0, 0, 0);
                }
            }
            __syncthreads();
            buf ^= 1;
        }
    }

    // ---- normalize & store styled_t[n][c] f16
    #pragma unroll
    for (int r = 0; r < 4; r++) {
        float linv = 1.0f / lrun[r];
        f16* drow = So + ((size_t)b*NSP + nw + l4*4 + r) * CH + l15;
        #pragma unroll
        for (int i = 0; i < 32; i++) drow[i*16] = (f16)(o_acc[i][r] * linv);
    }
}

// ---------------------------------------------------------------- launch
extern "C" void kernel_launch(void* const* d_in, const int* in_sizes, int n_in,
                              void* d_out, int out_size, void* d_ws, size_t ws_size,
                              hipStream_t stream)
{
    const float* content = (const float*)d_in[0];
    const float* style   = (const float*)d_in[1];
    const float* f_w = (const float*)d_in[2];
    const float* f_b = (const float*)d_in[3];
    const float* g_w = (const float*)d_in[4];
    const float* g_b = (const float*)d_in[5];
    const float* h_w = (const float*)d_in[6];
    const float* h_b = (const float*)d_in[7];
    const float* o_w = (const float*)d_in[8];
    const float* o_b = (const float*)d_in[9];

    char* ws = (char*)d_ws;
    size_t off = 0;
    auto alloc = [&](size_t bytes) -> void* {
        void* p = ws + off;
        off += (bytes + 255) & ~(size_t)255;
        return p;
    };
    float* stats = (float*)alloc(4 * NB*CH * 4);
    f16* fw_e = (f16*)alloc((size_t)NB*CH*CH*2);
    f16* gw_e = (f16*)alloc((size_t)NB*CH*CH*2);
    f16* hw_h = (f16*)alloc((size_t)CH*CH*2);
    f16* ow_h = (f16*)alloc((size_t)CH*CH*2);
    float* fb_e = (float*)alloc((size_t)NB*CH*4);
    float* gb_e = (float*)alloc((size_t)NB*CH*4);
    f16* content_t = (f16*)alloc((size_t)NB*NSP*CH*2);
    f16* style_t   = (f16*)alloc((size_t)NB*NSP*CH*2);
    f16* F_t = (f16*)alloc((size_t)NB*NSP*CH*2);
    f16* G_t = (f16*)alloc((size_t)NB*NSP*CH*2);
    f16* H_  = (f16*)alloc((size_t)NB*CH*NSP*2);
    f16* styled_t = content_t;   // content_t dead after F-GEMM; flash runs later -> safe alias
    if (off > ws_size) return;   // insufficient workspace; cannot proceed

    stats_kernel<<<dim3(2*NB*CH), dim3(256), 0, stream>>>(content, style, stats);
    effw_kernel<<<dim3(CH, NB, 4), dim3(128), 0, stream>>>(f_w, f_b, g_w, g_b, h_w, o_w, stats,
                                                           fw_e, fb_e, gw_e, gb_e, hw_h, ow_h);
    transpose_f16_kernel<<<dim3(NSP/64, CH/64, NB*2), dim3(256), 0, stream>>>(content, style, content_t, style_t);
    gemm_kernel<0><<<dim3(NSP/128, CH/128, NB), dim3(256), 0, stream>>>(
        fw_e, (long)CH*CH, content_t, fb_e, (long)CH, (void*)F_t, (long)NSP*CH);
    gemm_kernel<0><<<dim3(NSP/128, CH/128, NB), dim3(256), 0, stream>>>(
        gw_e, (long)CH*CH, style_t, gb_e, (long)CH, (void*)G_t, (long)NSP*CH);
    gemm_kernel<1><<<dim3(NSP/128, CH/128, NB), dim3(256), 0, stream>>>(
        hw_h, 0L, style_t, h_b, 0L, (void*)H_, (long)CH*NSP);
    flash_kernel<<<dim3(NSP/64, NB), dim3(256), 0, stream>>>(F_t, G_t, H_, styled_t);
    gemm_kernel<2><<<dim3(NSP/128, CH/128, NB), dim3(256), 0, stream>>>(
        ow_h, 0L, styled_t, o_b, 0L, d_out, (long)CH*NSP);
}

// Round 2
// 512.668 us; speedup vs baseline: 1.0114x; 1.0114x over previous
//
#include <hip/hip_runtime.h>
#include <hip/hip_bf16.h>

typedef _Float16 f16;
typedef __attribute__((ext_vector_type(8))) _Float16 half8;
typedef __attribute__((ext_vector_type(4))) _Float16 half4;
typedef __attribute__((ext_vector_type(4))) float f32x4;

#define AS1 __attribute__((address_space(1)))
#define AS3 __attribute__((address_space(3)))

constexpr int CH  = 512;    // channels
constexpr int NSP = 4096;   // 64*64 spatial
constexpr int NB  = 4;      // batch

#define VM16 asm volatile("s_waitcnt vmcnt(16)" ::: "memory")
#define VM8  asm volatile("s_waitcnt vmcnt(8)"  ::: "memory")
#define VM0  asm volatile("s_waitcnt vmcnt(0)"  ::: "memory")
#define BARS do { __builtin_amdgcn_s_barrier(); asm volatile("" ::: "memory"); } while (0)

__device__ __forceinline__ void gload_lds16(const void* g, void* l) {
    __builtin_amdgcn_global_load_lds((const AS1 void*)g, (AS3 void*)l, 16, 0, 0);
}

// ---------------------------------------------------------------- stats
__global__ void stats_kernel(const float* __restrict__ c_, const float* __restrict__ s_,
                             float* __restrict__ stats)
{
    int row = blockIdx.x;
    const float* p = ((row < NB*CH) ? c_ : s_) + (size_t)(row & (NB*CH - 1)) * NSP;
    float s = 0.f, ss = 0.f;
    for (int i = threadIdx.x; i < NSP/4; i += 256) {
        float4 v = ((const float4*)p)[i];
        s  += v.x + v.y + v.z + v.w;
        ss += v.x*v.x + v.y*v.y + v.z*v.z + v.w*v.w;
    }
    #pragma unroll
    for (int off = 32; off; off >>= 1) { s += __shfl_down(s, off); ss += __shfl_down(ss, off); }
    __shared__ float r1[4], r2[4];
    if ((threadIdx.x & 63) == 0) { r1[threadIdx.x >> 6] = s; r2[threadIdx.x >> 6] = ss; }
    __syncthreads();
    if (threadIdx.x == 0) {
        s = r1[0]+r1[1]+r1[2]+r1[3]; ss = r2[0]+r2[1]+r2[2]+r2[3];
        float mean = s * (1.f/NSP);
        float var  = (ss - (float)NSP*mean*mean) * (1.f/(NSP-1));
        int base = (row < NB*CH) ? 0 : 2*NB*CH;
        int r = row & (NB*CH - 1);
        stats[base + r] = mean;
        stats[base + NB*CH + r] = rsqrtf(var + 1e-5f);
    }
}

// ---------------------------------------------------------------- effective weights
__global__ void effw_kernel(const float* __restrict__ fw, const float* __restrict__ fb,
                            const float* __restrict__ gw, const float* __restrict__ gb,
                            const float* __restrict__ hw, const float* __restrict__ ow,
                            const float* __restrict__ stats,
                            f16* __restrict__ fw_e, float* __restrict__ fb_e,
                            f16* __restrict__ gw_e, float* __restrict__ gb_e,
                            f16* __restrict__ hw_h, f16* __restrict__ ow_h)
{
    int o = blockIdx.x, b = blockIdx.y, mode = blockIdx.z, t = threadIdx.x;
    if (mode >= 2) {
        if (b != 0) return;
        const float* srcw = (mode == 2) ? hw : ow;
        f16* dstw = (mode == 2) ? hw_h : ow_h;
        for (int c = t; c < CH; c += 128) dstw[o*CH + c] = (f16)srcw[o*CH + c];
        return;
    }
    const float* w  = mode ? gw : fw;
    const float* st = stats + (mode ? 2*NB*CH : 0);
    f16* we = mode ? gw_e : fw_e;
    float part = 0.f;
    for (int c = t; c < CH; c += 128) {
        float mn = st[b*CH + c], is = st[NB*CH + b*CH + c];
        float wv = w[o*CH + c];
        we[((size_t)b*CH + o)*CH + c] = (f16)(wv * is);
        part += wv * mn * is;
    }
    #pragma unroll
    for (int off = 32; off; off >>= 1) part += __shfl_down(part, off);
    __shared__ float rr[2];
    if ((t & 63) == 0) rr[t >> 6] = part;
    __syncthreads();
    if (t == 0) (mode ? gb_e : fb_e)[b*CH + o] = (mode ? gb : fb)[o] - (rr[0] + rr[1]);
}

// ---------------------------------------------------------------- transpose f32[c][n] -> f16[n][c]
__global__ void transpose_f16_kernel(const float* __restrict__ content, const float* __restrict__ style,
                                     f16* __restrict__ content_t, f16* __restrict__ style_t)
{
    int b = blockIdx.z & 3, is_style = blockIdx.z >> 2;
    const float* src = (is_style ? style : content) + (size_t)b * CH * NSP;
    f16* dst = (is_style ? style_t : content_t) + (size_t)b * NSP * CH;
    int c0 = blockIdx.y * 64, n0 = blockIdx.x * 64;
    __shared__ f16 tile[64][72];
    int t = threadIdx.x;
    #pragma unroll
    for (int i = 0; i < 4; i++) {
        int idx = t + i*256;
        int cr = idx >> 4, n4 = (idx & 15) * 4;
        float4 v = *(const float4*)(src + (size_t)(c0+cr)*NSP + n0 + n4);
        tile[cr][n4+0] = (f16)v.x; tile[cr][n4+1] = (f16)v.y;
        tile[cr][n4+2] = (f16)v.z; tile[cr][n4+3] = (f16)v.w;
    }
    __syncthreads();
    int nr = t >> 2, seg = (t & 3) * 16;
    __align__(16) f16 out_v[16];
    #pragma unroll
    for (int j = 0; j < 16; j++) out_v[j] = tile[seg + j][nr];
    f16* dp = dst + (size_t)(n0+nr)*CH + c0 + seg;
    *(int4*)dp = ((int4*)out_v)[0];
    *(int4*)(dp + 8) = ((int4*)out_v)[1];
}

// ---------------------------------------------------------------- GEMM  Y[o][n] = sum_c W[o][c]*Xt[n][c] + bias[o]
// counted-vmcnt double-buffer: stage(next); vmcnt(8); barrier; MFMA; barrier.
template<int MODE>
__global__ __launch_bounds__(256)
void gemm_kernel(const f16* __restrict__ W, long wstrideb,
                 const f16* __restrict__ Xt,
                 const float* __restrict__ bias, long bstrideb,
                 void* __restrict__ Y, long ystrideb)
{
    const int z = blockIdx.z;
    W    += (size_t)z * wstrideb;
    Xt   += (size_t)z * NSP * CH;
    bias += (size_t)z * bstrideb;
    const int m0 = blockIdx.y * 128, n0 = blockIdx.x * 128;
    const int t = threadIdx.x, wave = t >> 6, lane = t & 63;
    const int l15 = lane & 15, l4 = lane >> 4;
    const int wm = (wave >> 1) * 64, wn = (wave & 1) * 64;

    __shared__ __align__(16) f16 Al[2][8192];   // [128 rows][64 c], swizzled
    __shared__ __align__(16) f16 Bl[2][8192];

    f32x4 acc[4][4] = {};

    auto stage = [&](int bufi, int kk) {
        #pragma unroll
        for (int j = 0; j < 4; j++) {
            int L  = ((wave*4 + j)*64 + lane) * 16;
            int SL = L ^ (((L >> 7) & 7) << 4);
            int row = SL >> 7, seg = (SL & 127) >> 1;
            gload_lds16(W  + (size_t)(m0 + row)*CH + kk + seg, &Al[bufi][L >> 1]);
            gload_lds16(Xt + (size_t)(n0 + row)*CH + kk + seg, &Bl[bufi][L >> 1]);
        }
    };

    stage(0, 0);
    for (int ks = 0; ks < 8; ks++) {
        int bufi = ks & 1;
        if (ks < 7) { stage(bufi ^ 1, (ks + 1) * 64); VM8; }
        else        { VM0; }
        BARS;
        #pragma unroll
        for (int kb = 0; kb < 2; kb++) {
            half8 a[4], bb[4];
            #pragma unroll
            for (int i = 0; i < 4; i++) {
                int ab = (wm + i*16 + l15)*128 + kb*64 + l4*16;
                ab ^= ((ab >> 7) & 7) << 4;
                a[i] = *(const half8*)&Al[bufi][ab >> 1];
                int bby = (wn + i*16 + l15)*128 + kb*64 + l4*16;
                bby ^= ((bby >> 7) & 7) << 4;
                bb[i] = *(const half8*)&Bl[bufi][bby >> 1];
            }
            #pragma unroll
            for (int i = 0; i < 4; i++)
                #pragma unroll
                for (int jj = 0; jj < 4; jj++)
                    acc[i][jj] = __builtin_amdgcn_mfma_f32_16x16x32_f16(a[i], bb[jj], acc[i][jj], 0, 0, 0);
        }
        BARS;
    }

    #pragma unroll
    for (int i = 0; i < 4; i++) {
        const int ob = m0 + wm + i*16 + l4*4;
        f32x4 bv = *(const f32x4*)(bias + ob);
        #pragma unroll
        for (int jj = 0; jj < 4; jj++) {
            const int n = n0 + wn + jj*16 + l15;
            f32x4 v = acc[i][jj];
            v[0] += bv[0]; v[1] += bv[1]; v[2] += bv[2]; v[3] += bv[3];
            if constexpr (MODE == 0) {
                f16* Yb = (f16*)Y + (size_t)z * ystrideb;
                half4 pk; pk[0]=(f16)v[0]; pk[1]=(f16)v[1]; pk[2]=(f16)v[2]; pk[3]=(f16)v[3];
                *(half4*)(Yb + (size_t)n * CH + ob) = pk;
            } else if constexpr (MODE == 1) {
                f16* Yb = (f16*)Y + (size_t)z * ystrideb;
                #pragma unroll
                for (int r = 0; r < 4; r++) Yb[(size_t)(ob + r) * NSP + n] = (f16)v[r];
            } else {
                float* Yf = (float*)Y + (size_t)z * ystrideb;
                #pragma unroll
                for (int r = 0; r < 4; r++) Yf[(size_t)(ob + r) * NSP + n] = v[r];
            }
        }
    }
}

// ---------------------------------------------------------------- flash attention, 8-buffer counted-vmcnt ring
// per m-tile: 8 phases (K0..K3 compute / V0..V3 compute), each phase stages the chunk 4-ahead,
// then s_waitcnt vmcnt(16) + raw s_barrier. No vmcnt(0) drain in the loop.
__global__ __launch_bounds__(256, 1)
void flash_kernel(const f16* __restrict__ Ft, const f16* __restrict__ Gt,
                  const f16* __restrict__ Hm, f16* __restrict__ So)
{
    const int b = blockIdx.y;
    const int n0 = blockIdx.x * 64;
    const int t = threadIdx.x, wave = t >> 6, lane = t & 63;
    const int l15 = lane & 15, l4 = lane >> 4;
    const int nw = n0 + wave * 16;

    __shared__ __align__(16) f16 KV[8][8192];        // bufs 0-3: K [64m][128c]; bufs 4-7: V [128c][64m]
    __shared__ __align__(16) f16 P_lds[4][16][72];   // per-wave P (private to wave)

    half8 q[16];
    {
        const f16* qp = Ft + ((size_t)b*NSP + nw + l15) * CH + l4*8;
        #pragma unroll
        for (int kb = 0; kb < 16; kb++) q[kb] = *(const half8*)(qp + kb*32);
    }

    f32x4 o_acc[32] = {};
    float mrun[4] = {-1e30f,-1e30f,-1e30f,-1e30f};
    float lrun[4] = {0.f,0.f,0.f,0.f};

    const f16* Gb = Gt + (size_t)b * NSP * CH;
    const f16* Hb = Hm + (size_t)b * CH * NSP;

    auto stageK = [&](int bufi, int mm0, int cc) {
        #pragma unroll
        for (int j = 0; j < 4; j++) {
            int L  = ((wave*4 + j)*64 + lane) * 16;
            int SL = L ^ (((L >> 8) & 7) << 4);
            gload_lds16(Gb + (size_t)(mm0 + (SL >> 8)) * CH + cc*128 + ((SL & 255) >> 1),
                        &KV[bufi][L >> 1]);
        }
    };
    auto stageV = [&](int bufi, int mm0, int cc) {
        #pragma unroll
        for (int j = 0; j < 4; j++) {
            int L  = ((wave*4 + j)*64 + lane) * 16;
            int SL = L ^ (((L >> 7) & 7) << 4);
            gload_lds16(Hb + (size_t)(cc*128 + (SL >> 7)) * NSP + mm0 + ((SL & 127) >> 1),
                        &KV[bufi][L >> 1]);
        }
    };

    // prologue: K chunks of m-tile 0 into bufs 0..3
    stageK(0, 0, 0); stageK(1, 0, 1); stageK(2, 0, 2); stageK(3, 0, 3);

    for (int m0 = 0; m0 < NSP; m0 += 64) {
        const int nm0 = (m0 + 64 < NSP) ? (m0 + 64) : 0;
        f32x4 s[4] = {};

        // ---- QK phases: compute K chunk cc from buf cc; stage V chunk cc into buf 4+cc
        #pragma unroll
        for (int cc = 0; cc < 4; cc++) {
            stageV(4 + cc, m0, cc);
            VM16; BARS;
            #pragma unroll
            for (int kb = 0; kb < 4; kb++) {
                half8 a = q[cc*4 + kb];
                #pragma unroll
                for (int mc = 0; mc < 4; mc++) {
                    int byt = (mc*16 + l15)*256 + kb*64 + l4*16;
                    byt ^= ((byt >> 8) & 7) << 4;
                    half8 bb = *(const half8*)&KV[cc][byt >> 1];
                    s[mc] = __builtin_amdgcn_mfma_f32_16x16x32_f16(a, bb, s[mc], 0, 0, 0);
                }
            }
        }

        // ---- online softmax (wave-private); defer-max rescale (T13, THR=8)
        float mx[4];
        #pragma unroll
        for (int r = 0; r < 4; r++) {
            float m_ = fmaxf(fmaxf(s[0][r], s[1][r]), fmaxf(s[2][r], s[3][r]));
            #pragma unroll
            for (int off = 8; off; off >>= 1) m_ = fmaxf(m_, __shfl_xor(m_, off));
            mx[r] = m_;
        }
        bool grow = (mx[0] > mrun[0]+8.f) | (mx[1] > mrun[1]+8.f) |
                    (mx[2] > mrun[2]+8.f) | (mx[3] > mrun[3]+8.f);
        if (__any(grow)) {
            float scale_[4];
            #pragma unroll
            for (int r = 0; r < 4; r++) {
                float mnew = fmaxf(mrun[r], mx[r]);
                scale_[r] = __expf(mrun[r] - mnew);
                float ps = 0.f;
                #pragma unroll
                for (int mc = 0; mc < 4; mc++) {
                    float p = __expf(s[mc][r] - mnew);
                    s[mc][r] = p; ps += p;
                }
                #pragma unroll
                for (int off = 8; off; off >>= 1) ps += __shfl_xor(ps, off);
                lrun[r] = lrun[r] * scale_[r] + ps;
                mrun[r] = mnew;
            }
            #pragma unroll
            for (int i = 0; i < 32; i++) {
                o_acc[i][0] *= scale_[0]; o_acc[i][1] *= scale_[1];
                o_acc[i][2] *= scale_[2]; o_acc[i][3] *= scale_[3];
            }
        } else {
            #pragma unroll
            for (int r = 0; r < 4; r++) {
                float ps = 0.f;
                #pragma unroll
                for (int mc = 0; mc < 4; mc++) {
                    float p = __expf(s[mc][r] - mrun[r]);
                    s[mc][r] = p; ps += p;
                }
                #pragma unroll
                for (int off = 8; off; off >>= 1) ps += __shfl_xor(ps, off);
                lrun[r] += ps;
            }
        }
        #pragma unroll
        for (int mc = 0; mc < 4; mc++)
            #pragma unroll
            for (int r = 0; r < 4; r++)
                P_lds[wave][l4*4 + r][mc*16 + l15] = (f16)s[mc][r];

        // ---- PV phases: compute V chunk vcc from buf 4+vcc; stage K chunk vcc of next tile into buf vcc
        #pragma unroll
        for (int vcc = 0; vcc < 4; vcc++) {
            stageK(vcc, nm0, vcc);
            VM16; BARS;
            #pragma unroll
            for (int kb = 0; kb < 2; kb++) {
                half8 pb = *(const half8*)&P_lds[wave][l15][kb*32 + l4*8];
                #pragma unroll
                for (int cb = 0; cb < 8; cb++) {
                    int ab = (cb*16 + l15)*128 + kb*64 + l4*16;
                    ab ^= ((ab >> 7) & 7) << 4;
                    half8 vv = *(const half8*)&KV[4 + vcc][ab >> 1];
                    o_acc[vcc*8 + cb] = __builtin_amdgcn_mfma_f32_16x16x32_f16(pb, vv, o_acc[vcc*8 + cb], 0, 0, 0);
                }
            }
        }
    }
    VM0;  // drain straggler gload_lds before LDS dealloc

    #pragma unroll
    for (int r = 0; r < 4; r++) {
        float linv = 1.0f / lrun[r];
        f16* drow = So + ((size_t)b*NSP + nw + l4*4 + r) * CH + l15;
        #pragma unroll
        for (int i = 0; i < 32; i++) drow[i*16] = (f16)(o_acc[i][r] * linv);
    }
}

// ---------------------------------------------------------------- launch
extern "C" void kernel_launch(void* const* d_in, const int* in_sizes, int n_in,
                              void* d_out, int out_size, void* d_ws, size_t ws_size,
                              hipStream_t stream)
{
    const float* content = (const float*)d_in[0];
    const float* style   = (const float*)d_in[1];
    const float* f_w = (const float*)d_in[2];
    const float* f_b = (const float*)d_in[3];
    const float* g_w = (const float*)d_in[4];
    const float* g_b = (const float*)d_in[5];
    const float* h_w = (const float*)d_in[6];
    const float* h_b = (const float*)d_in[7];
    const float* o_w = (const float*)d_in[8];
    const float* o_b = (const float*)d_in[9];

    char* ws = (char*)d_ws;
    size_t off = 0;
    auto alloc = [&](size_t bytes) -> void* {
        void* p = ws + off;
        off += (bytes + 255) & ~(size_t)255;
        return p;
    };
    float* stats = (float*)alloc(4 * NB*CH * 4);
    f16* fw_e = (f16*)alloc((size_t)NB*CH*CH*2);
    f16* gw_e = (f16*)alloc((size_t)NB*CH*CH*2);
    f16* hw_h = (f16*)alloc((size_t)CH*CH*2);
    f16* ow_h = (f16*)alloc((size_t)CH*CH*2);
    float* fb_e = (float*)alloc((size_t)NB*CH*4);
    float* gb_e = (float*)alloc((size_t)NB*CH*4);
    f16* content_t = (f16*)alloc((size_t)NB*NSP*CH*2);
    f16* style_t   = (f16*)alloc((size_t)NB*NSP*CH*2);
    f16* F_t = (f16*)alloc((size_t)NB*NSP*CH*2);
    f16* G_t = (f16*)alloc((size_t)NB*NSP*CH*2);
    f16* H_  = (f16*)alloc((size_t)NB*CH*NSP*2);
    f16* styled_t = content_t;   // content_t dead after F-GEMM; flash runs later -> safe alias
    if (off > ws_size) return;

    stats_kernel<<<dim3(2*NB*CH), dim3(256), 0, stream>>>(content, style, stats);
    effw_kernel<<<dim3(CH, NB, 4), dim3(128), 0, stream>>>(f_w, f_b, g_w, g_b, h_w, o_w, stats,
                                                           fw_e, fb_e, gw_e, gb_e, hw_h, ow_h);
    transpose_f16_kernel<<<dim3(NSP/64, CH/64, NB*2), dim3(256), 0, stream>>>(content, style, content_t, style_t);
    gemm_kernel<0><<<dim3(NSP/128, CH/128, NB), dim3(256), 0, stream>>>(
        fw_e, (long)CH*CH, content_t, fb_e, (long)CH, (void*)F_t, (long)NSP*CH);
    gemm_kernel<0><<<dim3(NSP/128, CH/128, NB), dim3(256), 0, stream>>>(
        gw_e, (long)CH*CH, style_t, gb_e, (long)CH, (void*)G_t, (long)NSP*CH);
    gemm_kernel<1><<<dim3(NSP/128, CH/128, NB), dim3(256), 0, stream>>>(
        hw_h, 0L, style_t, h_b, 0L, (void*)H_, (long)CH*NSP);
    flash_kernel<<<dim3(NSP/64, NB), dim3(256), 0, stream>>>(F_t, G_t, H_, styled_t);
    gemm_kernel<2><<<dim3(NSP/128, CH/128, NB), dim3(256), 0, stream>>>(
        ow_h, 0L, styled_t, o_b, 0L, d_out, (long)CH*NSP);
}

// Round 3
// 343.731 us; speedup vs baseline: 1.5085x; 1.4915x over previous
//
#include <hip/hip_runtime.h>
#include <hip/hip_bf16.h>

typedef _Float16 f16;
typedef __attribute__((ext_vector_type(8))) _Float16 half8;
typedef __attribute__((ext_vector_type(4))) _Float16 half4;
typedef __attribute__((ext_vector_type(4))) float f32x4;

#define AS1 __attribute__((address_space(1)))
#define AS3 __attribute__((address_space(3)))

constexpr int CH  = 512;    // channels
constexpr int NSP = 4096;   // 64*64 spatial
constexpr int NB  = 4;      // batch

#define VM8  asm volatile("s_waitcnt vmcnt(8)"  ::: "memory")
#define VM0  asm volatile("s_waitcnt vmcnt(0)"  ::: "memory")
#define BARS do { __builtin_amdgcn_s_barrier(); asm volatile("" ::: "memory"); } while (0)

__device__ __forceinline__ void gload_lds16(const void* g, void* l) {
    __builtin_amdgcn_global_load_lds((const AS1 void*)g, (AS3 void*)l, 16, 0, 0);
}

// ---------------------------------------------------------------- stats
__global__ void stats_kernel(const float* __restrict__ c_, const float* __restrict__ s_,
                             float* __restrict__ stats)
{
    int row = blockIdx.x;
    const float* p = ((row < NB*CH) ? c_ : s_) + (size_t)(row & (NB*CH - 1)) * NSP;
    float s = 0.f, ss = 0.f;
    for (int i = threadIdx.x; i < NSP/4; i += 256) {
        float4 v = ((const float4*)p)[i];
        s  += v.x + v.y + v.z + v.w;
        ss += v.x*v.x + v.y*v.y + v.z*v.z + v.w*v.w;
    }
    #pragma unroll
    for (int off = 32; off; off >>= 1) { s += __shfl_down(s, off); ss += __shfl_down(ss, off); }
    __shared__ float r1[4], r2[4];
    if ((threadIdx.x & 63) == 0) { r1[threadIdx.x >> 6] = s; r2[threadIdx.x >> 6] = ss; }
    __syncthreads();
    if (threadIdx.x == 0) {
        s = r1[0]+r1[1]+r1[2]+r1[3]; ss = r2[0]+r2[1]+r2[2]+r2[3];
        float mean = s * (1.f/NSP);
        float var  = (ss - (float)NSP*mean*mean) * (1.f/(NSP-1));
        int base = (row < NB*CH) ? 0 : 2*NB*CH;
        int r = row & (NB*CH - 1);
        stats[base + r] = mean;
        stats[base + NB*CH + r] = rsqrtf(var + 1e-5f);
    }
}

// ---------------------------------------------------------------- effective weights
__global__ void effw_kernel(const float* __restrict__ fw, const float* __restrict__ fb,
                            const float* __restrict__ gw, const float* __restrict__ gb,
                            const float* __restrict__ hw, const float* __restrict__ ow,
                            const float* __restrict__ stats,
                            f16* __restrict__ fw_e, float* __restrict__ fb_e,
                            f16* __restrict__ gw_e, float* __restrict__ gb_e,
                            f16* __restrict__ hw_h, f16* __restrict__ ow_h)
{
    int o = blockIdx.x, b = blockIdx.y, mode = blockIdx.z, t = threadIdx.x;
    if (mode >= 2) {
        if (b != 0) return;
        const float* srcw = (mode == 2) ? hw : ow;
        f16* dstw = (mode == 2) ? hw_h : ow_h;
        for (int c = t; c < CH; c += 128) dstw[o*CH + c] = (f16)srcw[o*CH + c];
        return;
    }
    const float* w  = mode ? gw : fw;
    const float* st = stats + (mode ? 2*NB*CH : 0);
    f16* we = mode ? gw_e : fw_e;
    float part = 0.f;
    for (int c = t; c < CH; c += 128) {
        float mn = st[b*CH + c], is = st[NB*CH + b*CH + c];
        float wv = w[o*CH + c];
        we[((size_t)b*CH + o)*CH + c] = (f16)(wv * is);
        part += wv * mn * is;
    }
    #pragma unroll
    for (int off = 32; off; off >>= 1) part += __shfl_down(part, off);
    __shared__ float rr[2];
    if ((t & 63) == 0) rr[t >> 6] = part;
    __syncthreads();
    if (t == 0) (mode ? gb_e : fb_e)[b*CH + o] = (mode ? gb : fb)[o] - (rr[0] + rr[1]);
}

// ---------------------------------------------------------------- transpose f32[c][n] -> f16[n][c]
__global__ void transpose_f16_kernel(const float* __restrict__ content, const float* __restrict__ style,
                                     f16* __restrict__ content_t, f16* __restrict__ style_t)
{
    int b = blockIdx.z & 3, is_style = blockIdx.z >> 2;
    const float* src = (is_style ? style : content) + (size_t)b * CH * NSP;
    f16* dst = (is_style ? style_t : content_t) + (size_t)b * NSP * CH;
    int c0 = blockIdx.y * 64, n0 = blockIdx.x * 64;
    __shared__ f16 tile[64][72];
    int t = threadIdx.x;
    #pragma unroll
    for (int i = 0; i < 4; i++) {
        int idx = t + i*256;
        int cr = idx >> 4, n4 = (idx & 15) * 4;
        float4 v = *(const float4*)(src + (size_t)(c0+cr)*NSP + n0 + n4);
        tile[cr][n4+0] = (f16)v.x; tile[cr][n4+1] = (f16)v.y;
        tile[cr][n4+2] = (f16)v.z; tile[cr][n4+3] = (f16)v.w;
    }
    __syncthreads();
    int nr = t >> 2, seg = (t & 3) * 16;
    __align__(16) f16 out_v[16];
    #pragma unroll
    for (int j = 0; j < 16; j++) out_v[j] = tile[seg + j][nr];
    f16* dp = dst + (size_t)(n0+nr)*CH + c0 + seg;
    *(int4*)dp = ((int4*)out_v)[0];
    *(int4*)(dp + 8) = ((int4*)out_v)[1];
}

// ---------------------------------------------------------------- generalized GEMM
// Y[ob][n] = sum_k W[ob][k]*Xt[n][k] + bias[ob], K runtime (multiple of 64), row stride of W/Xt = K.
// MODE 0: f16 transposed store Y_t[n][ob] (row stride = ostride)
// MODE 1: f16 store Y[ob][n] (row stride = ostride)
// MODE 2: f32 store Y[ob][n] (row stride = ostride)
// 128x128 tile, BK=64, 4 waves, global_load_lds + XOR swizzle, counted-vmcnt double buffer.
template<int MODE>
__global__ __launch_bounds__(256)
void gemm_kernel(const f16* __restrict__ W, long wstrideb,
                 const f16* __restrict__ Xt, long xstrideb,
                 const float* __restrict__ bias, long bstrideb,
                 void* __restrict__ Y, long ystrideb,
                 int K, long ostride)
{
    const int z = blockIdx.z;
    W    += (size_t)z * wstrideb;
    Xt   += (size_t)z * xstrideb;
    bias += (size_t)z * bstrideb;
    const int m0 = blockIdx.y * 128, n0 = blockIdx.x * 128;
    const int t = threadIdx.x, wave = t >> 6, lane = t & 63;
    const int l15 = lane & 15, l4 = lane >> 4;
    const int wm = (wave >> 1) * 64, wn = (wave & 1) * 64;

    __shared__ __align__(16) f16 Al[2][8192];   // [128 rows][64 k], swizzled
    __shared__ __align__(16) f16 Bl[2][8192];

    f32x4 acc[4][4] = {};

    auto stage = [&](int bufi, int kk) {
        #pragma unroll
        for (int j = 0; j < 4; j++) {
            int L  = ((wave*4 + j)*64 + lane) * 16;
            int SL = L ^ (((L >> 7) & 7) << 4);
            int row = SL >> 7, seg = (SL & 127) >> 1;
            gload_lds16(W  + (size_t)(m0 + row)*K + kk + seg, &Al[bufi][L >> 1]);
            gload_lds16(Xt + (size_t)(n0 + row)*K + kk + seg, &Bl[bufi][L >> 1]);
        }
    };

    const int nks = K >> 6;
    stage(0, 0);
    for (int ks = 0; ks < nks; ks++) {
        int bufi = ks & 1;
        if (ks < nks-1) { stage(bufi ^ 1, (ks + 1) * 64); VM8; }
        else            { VM0; }
        BARS;
        #pragma unroll
        for (int kb = 0; kb < 2; kb++) {
            half8 a[4], bb[4];
            #pragma unroll
            for (int i = 0; i < 4; i++) {
                int ab = (wm + i*16 + l15)*128 + kb*64 + l4*16;
                ab ^= ((ab >> 7) & 7) << 4;
                a[i] = *(const half8*)&Al[bufi][ab >> 1];
                int bby = (wn + i*16 + l15)*128 + kb*64 + l4*16;
                bby ^= ((bby >> 7) & 7) << 4;
                bb[i] = *(const half8*)&Bl[bufi][bby >> 1];
            }
            #pragma unroll
            for (int i = 0; i < 4; i++)
                #pragma unroll
                for (int jj = 0; jj < 4; jj++)
                    acc[i][jj] = __builtin_amdgcn_mfma_f32_16x16x32_f16(a[i], bb[jj], acc[i][jj], 0, 0, 0);
        }
        BARS;
    }

    #pragma unroll
    for (int i = 0; i < 4; i++) {
        const int ob = m0 + wm + i*16 + l4*4;
        f32x4 bv = *(const f32x4*)(bias + ob);
        #pragma unroll
        for (int jj = 0; jj < 4; jj++) {
            const int n = n0 + wn + jj*16 + l15;
            f32x4 v = acc[i][jj];
            v[0] += bv[0]; v[1] += bv[1]; v[2] += bv[2]; v[3] += bv[3];
            if constexpr (MODE == 0) {
                f16* Yb = (f16*)Y + (size_t)z * ystrideb;
                half4 pk; pk[0]=(f16)v[0]; pk[1]=(f16)v[1]; pk[2]=(f16)v[2]; pk[3]=(f16)v[3];
                *(half4*)(Yb + (size_t)n * ostride + ob) = pk;
            } else if constexpr (MODE == 1) {
                f16* Yb = (f16*)Y + (size_t)z * ystrideb;
                #pragma unroll
                for (int r = 0; r < 4; r++) Yb[(size_t)(ob + r) * ostride + n] = (f16)v[r];
            } else {
                float* Yf = (float*)Y + (size_t)z * ystrideb;
                #pragma unroll
                for (int r = 0; r < 4; r++) Yf[(size_t)(ob + r) * ostride + n] = v[r];
            }
        }
    }
}

// ---------------------------------------------------------------- row softmax (in place, f16)
// one wave per row of 4096; 4 rows per block. f32 math.
__global__ __launch_bounds__(256)
void softmax_kernel(f16* __restrict__ S, int nrows)
{
    int row = blockIdx.x * 4 + (threadIdx.x >> 6);
    if (row >= nrows) return;
    int lane = threadIdx.x & 63;
    f16* p = S + (size_t)row * NSP + lane * 8;

    half8 v[8];
    #pragma unroll
    for (int j = 0; j < 8; j++) v[j] = *(const half8*)(p + j * 512);

    float mx = -1e30f;
    #pragma unroll
    for (int j = 0; j < 8; j++)
        #pragma unroll
        for (int e = 0; e < 8; e++) mx = fmaxf(mx, (float)v[j][e]);
    #pragma unroll
    for (int off = 32; off; off >>= 1) mx = fmaxf(mx, __shfl_xor(mx, off));

    float ex[64];
    float s = 0.f;
    #pragma unroll
    for (int j = 0; j < 8; j++)
        #pragma unroll
        for (int e = 0; e < 8; e++) {
            float x = __expf((float)v[j][e] - mx);
            ex[j*8 + e] = x; s += x;
        }
    #pragma unroll
    for (int off = 32; off; off >>= 1) s += __shfl_xor(s, off);
    float inv = 1.0f / s;

    #pragma unroll
    for (int j = 0; j < 8; j++) {
        half8 o;
        #pragma unroll
        for (int e = 0; e < 8; e++) o[e] = (f16)(ex[j*8 + e] * inv);
        *(half8*)(p + j * 512) = o;
    }
}

// ---------------------------------------------------------------- launch
extern "C" void kernel_launch(void* const* d_in, const int* in_sizes, int n_in,
                              void* d_out, int out_size, void* d_ws, size_t ws_size,
                              hipStream_t stream)
{
    const float* content = (const float*)d_in[0];
    const float* style   = (const float*)d_in[1];
    const float* f_w = (const float*)d_in[2];
    const float* f_b = (const float*)d_in[3];
    const float* g_w = (const float*)d_in[4];
    const float* g_b = (const float*)d_in[5];
    const float* h_w = (const float*)d_in[6];
    const float* h_b = (const float*)d_in[7];
    const float* o_w = (const float*)d_in[8];
    const float* o_b = (const float*)d_in[9];

    char* ws = (char*)d_ws;
    size_t off = 0;
    auto alloc = [&](size_t bytes) -> void* {
        void* p = ws + off;
        off += (bytes + 255) & ~(size_t)255;
        return p;
    };
    float* stats = (float*)alloc(4 * NB*CH * 4);
    float* zeros = (float*)alloc(NSP * 4);
    f16* fw_e = (f16*)alloc((size_t)NB*CH*CH*2);
    f16* gw_e = (f16*)alloc((size_t)NB*CH*CH*2);
    f16* hw_h = (f16*)alloc((size_t)CH*CH*2);
    f16* ow_h = (f16*)alloc((size_t)CH*CH*2);
    float* fb_e = (float*)alloc((size_t)NB*CH*4);
    float* gb_e = (float*)alloc((size_t)NB*CH*4);
    f16* content_t = (f16*)alloc((size_t)NB*NSP*CH*2);
    f16* style_t   = (f16*)alloc((size_t)NB*NSP*CH*2);
    f16* F_t = (f16*)alloc((size_t)NB*NSP*CH*2);
    f16* G_t = (f16*)alloc((size_t)NB*NSP*CH*2);
    f16* H_  = (f16*)alloc((size_t)NB*CH*NSP*2);
    f16* styled_t = content_t;           // content_t dead after F-GEMM

    // S buffer: tier 1 = all 4 batches (134 MB), tier 2 = one batch (34 MB) looped
    size_t s_plane = (size_t)NSP * NSP;  // elements per batch
    bool all4 = (off + 4 * s_plane * 2 <= ws_size);
    f16* S16 = (f16*)alloc((all4 ? 4 : 1) * s_plane * 2);
    if (off > ws_size) return;           // insufficient workspace: fail loud

    hipMemsetAsync(zeros, 0, NSP * 4, stream);
    stats_kernel<<<dim3(2*NB*CH), dim3(256), 0, stream>>>(content, style, stats);
    effw_kernel<<<dim3(CH, NB, 4), dim3(128), 0, stream>>>(f_w, f_b, g_w, g_b, h_w, o_w, stats,
                                                           fw_e, fb_e, gw_e, gb_e, hw_h, ow_h);
    transpose_f16_kernel<<<dim3(NSP/64, CH/64, NB*2), dim3(256), 0, stream>>>(content, style, content_t, style_t);

    // conv GEMMs (K=512): F, G (normalized via folded weights), H (plain)
    gemm_kernel<0><<<dim3(NSP/128, CH/128, NB), dim3(256), 0, stream>>>(
        fw_e, (long)CH*CH, content_t, (long)NSP*CH, fb_e, (long)CH, (void*)F_t, (long)NSP*CH, CH, (long)CH);
    gemm_kernel<0><<<dim3(NSP/128, CH/128, NB), dim3(256), 0, stream>>>(
        gw_e, (long)CH*CH, style_t, (long)NSP*CH, gb_e, (long)CH, (void*)G_t, (long)NSP*CH, CH, (long)CH);
    gemm_kernel<1><<<dim3(NSP/128, CH/128, NB), dim3(256), 0, stream>>>(
        hw_h, 0L, style_t, (long)NSP*CH, h_b, 0L, (void*)H_, (long)CH*NSP, CH, (long)NSP);

    if (all4) {
        // S[b][n][m] = F_t[b][n][:] . G_t[b][m][:]   (W = G_t -> ob = m; Xt = F_t -> rows n)
        gemm_kernel<0><<<dim3(NSP/128, NSP/128, NB), dim3(256), 0, stream>>>(
            G_t, (long)NSP*CH, F_t, (long)NSP*CH, zeros, 0L, (void*)S16, (long)s_plane, CH, (long)NSP);
        softmax_kernel<<<dim3(NB*NSP/4), dim3(256), 0, stream>>>(S16, NB*NSP);
        // styled_t[b][n][c] = sum_m H[b][c][m] * P[b][n][m]   (W = H_ -> ob = c; Xt = P; K = 4096)
        gemm_kernel<0><<<dim3(NSP/128, CH/128, NB), dim3(256), 0, stream>>>(
            H_, (long)CH*NSP, S16, (long)s_plane, zeros, 0L, (void*)styled_t, (long)NSP*CH, NSP, (long)CH);
    } else {
        for (int b = 0; b < NB; b++) {
            gemm_kernel<0><<<dim3(NSP/128, NSP/128, 1), dim3(256), 0, stream>>>(
                G_t + (size_t)b*NSP*CH, 0L, F_t + (size_t)b*NSP*CH, 0L, zeros, 0L,
                (void*)S16, 0L, CH, (long)NSP);
            softmax_kernel<<<dim3(NSP/4), dim3(256), 0, stream>>>(S16, NSP);
            gemm_kernel<0><<<dim3(NSP/128, CH/128, 1), dim3(256), 0, stream>>>(
                H_ + (size_t)b*CH*NSP, 0L, S16, 0L, zeros, 0L,
                (void*)(styled_t + (size_t)b*NSP*CH), 0L, NSP, (long)CH);
        }
    }

    // out = conv1x1(styled): f32 output
    gemm_kernel<2><<<dim3(NSP/128, CH/128, NB), dim3(256), 0, stream>>>(
        ow_h, 0L, styled_t, (long)NSP*CH, o_b, 0L, d_out, (long)CH*NSP, CH, (long)NSP);
}